// Round 6
// baseline (288.904 us; speedup 1.0000x reference)
//
#include <hip/hip_runtime.h>

// Shapes fixed by the reference: T=4, F=64, row = T*F = 256 elems (512 B bf16).
#define TF 256

typedef __attribute__((ext_vector_type(8))) short short8;
typedef __attribute__((ext_vector_type(4))) float f32x4;
typedef __attribute__((ext_vector_type(4))) unsigned int uint4v;

// ---------- bf16 helpers (fp32 <-> bf16, RNE) ----------
__device__ inline unsigned short f2bf(float x) {
  unsigned u = __float_as_uint(x);
  u += 0x7fffu + ((u >> 16) & 1u);
  return (unsigned short)(u >> 16);
}
__device__ inline unsigned pack2(unsigned short lo, unsigned short hi) {
  return (unsigned)lo | ((unsigned)hi << 16);
}
__device__ inline float bflo(unsigned u) { return __uint_as_float(u << 16); }
__device__ inline float bfhi(unsigned u) { return __uint_as_float(u & 0xffff0000u); }

__global__ void hist_kernel(const int* __restrict__ dst, int* __restrict__ indeg, int E) {
  int e = blockIdx.x * blockDim.x + threadIdx.x;
  if (e < E) atomicAdd(&indeg[dst[e]], 1);
}

// ---------- hierarchical scan ----------
__global__ __launch_bounds__(1024) void scan_part1(const int* __restrict__ indeg,
                                                   int* __restrict__ partials, int n) {
  __shared__ int wsum[16];
  const int tid = threadIdx.x;
  const int lane = tid & 63;
  const int wid = tid >> 6;
  int i = blockIdx.x * 1024 + tid;
  int s = (i < n) ? indeg[i] : 0;
  #pragma unroll
  for (int o = 1; o < 64; o <<= 1) s += __shfl_xor(s, o, 64);
  if (lane == 0) wsum[wid] = s;
  __syncthreads();
  if (tid == 0) {
    int acc = 0;
    #pragma unroll
    for (int w = 0; w < 16; ++w) acc += wsum[w];
    partials[blockIdx.x] = acc;
  }
}

__global__ __launch_bounds__(64) void scan_part2(const int* __restrict__ partials,
                                                 int* __restrict__ base,
                                                 int* __restrict__ offsets, int nb, int n) {
  const int i = threadIdx.x;
  int v = (i < nb) ? partials[i] : 0;
  int s = v;
  #pragma unroll
  for (int o = 1; o < 64; o <<= 1) {
    int t = __shfl_up(s, o, 64);
    if (i >= o) s += t;
  }
  if (i < nb) base[i] = s - v;
  if (i == nb - 1) offsets[n] = s;
}

__global__ __launch_bounds__(1024) void scan_part3(const int* __restrict__ indeg,
                                                   const int* __restrict__ base,
                                                   int* __restrict__ offsets,
                                                   int* __restrict__ cursor, int n) {
  __shared__ int wsum[16];
  const int tid = threadIdx.x;
  const int lane = tid & 63;
  const int wid = tid >> 6;
  int i = blockIdx.x * 1024 + tid;
  int v = (i < n) ? indeg[i] : 0;
  int s = v;
  #pragma unroll
  for (int o = 1; o < 64; o <<= 1) {
    int t = __shfl_up(s, o, 64);
    if (lane >= o) s += t;
  }
  if (lane == 63) wsum[wid] = s;
  __syncthreads();
  if (tid == 0) {
    int acc = 0;
    #pragma unroll
    for (int w = 0; w < 16; ++w) { int t = wsum[w]; wsum[w] = acc; acc += t; }
  }
  __syncthreads();
  int excl = s - v + wsum[wid] + base[blockIdx.x];
  if (i < n) { offsets[i] = excl; cursor[i] = excl; }
}

// Scatter edges into CSR slots: ONE 16B entry {srcB, pack(w0,w1), pack(w2,w3), 0},
// weights bf16, written non-temporally (stream-once data; avoid RFO/L2 ping-pong).
__global__ void fill_kernel(const int* __restrict__ src, const int* __restrict__ dst,
                            const float* __restrict__ ew, int* __restrict__ cursor,
                            uint4v* __restrict__ csr_ent, int E) {
  int e = blockIdx.x * blockDim.x + threadIdx.x;
  if (e >= E) return;
  int d = dst[e];
  int pos = atomicAdd(&cursor[d], 1);
  uint4v ent;
  ent.x = (unsigned)(src[e] << 9);  // row byte offset
  ent.y = pack2(f2bf(ew[e]), f2bf(ew[(size_t)E + e]));
  ent.z = pack2(f2bf(ew[2 * (size_t)E + e]), f2bf(ew[3 * (size_t)E + e]));
  ent.w = 0u;
  __builtin_nontemporal_store(ent, &csr_ent[pos]);
}

// h0_bf16 = bf16(node_features + pe[identities[t]]); 4 elems/thread
__global__ void prep_kernel(const float* __restrict__ x, const float* __restrict__ pe,
                            const int* __restrict__ ids, uint2* __restrict__ h0, int n4) {
  int i = blockIdx.x * blockDim.x + threadIdx.x;
  const int stride = gridDim.x * blockDim.x;
  for (; i < n4; i += stride) {
    int e0 = (i << 2) & (TF - 1);
    int t = e0 >> 6;
    int f4 = e0 & 63;
    float4 v = reinterpret_cast<const float4*>(x)[i];
    float4 p = *reinterpret_cast<const float4*>(&pe[ids[t] * 64 + f4]);
    uint2 o;
    o.x = pack2(f2bf(v.x + p.x), f2bf(v.y + p.y));
    o.y = pack2(f2bf(v.z + p.z), f2bf(v.w + p.w));
    h0[i] = o;
  }
}

// One wave per node; 32 lanes cover one 512 B row (uint4 = 16 B/lane), the wave
// processes 2 edges per pair (p = lane>>5), 4 pairs (8 edges) per main iteration ->
// 4 independent entry->row load chains in flight. shfl_xor(32) combines halves.
// LAYER 1 applies relu(y*scale+shift) (layer-0 BN) to gathered values on the fly.
template <int LAYER>
__global__ __launch_bounds__(256) void aggregate_kernel(
    const char* __restrict__ h_base, const int* __restrict__ offsets,
    const uint4* __restrict__ csr_ent,
    const float* __restrict__ scale, const float* __restrict__ shiftv,
    uint4* __restrict__ agg, int n_nodes) {
  const int lane = threadIdx.x & 63;
  const int wid = threadIdx.x >> 6;
  const int v = blockIdx.x * 4 + wid;
  if (v >= n_nodes) return;
  const int p = lane >> 5;       // which edge of the pair
  const unsigned q = lane & 31;  // 16B chunk within the row
  const unsigned qb = q << 4;    // byte offset within row
  const int tw = q >> 3;         // time index for the weight

  float sc[8], sh[8];
  if (LAYER == 1) {
    const int f0 = (q & 7) << 3;
    #pragma unroll
    for (int j = 0; j < 8; ++j) { sc[j] = scale[f0 + j]; sh[j] = shiftv[f0 + j]; }
  }

  float acc[8];
  #pragma unroll
  for (int j = 0; j < 8; ++j) acc[j] = 0.f;

  auto wext = [&](uint4 ent) -> float {
    unsigned word = (tw & 2) ? ent.z : ent.y;
    return (tw & 1) ? bfhi(word) : bflo(word);
  };
  auto body = [&](uint4 u, float w) {
    float x[8] = {bflo(u.x), bfhi(u.x), bflo(u.y), bfhi(u.y),
                  bflo(u.z), bfhi(u.z), bflo(u.w), bfhi(u.w)};
    #pragma unroll
    for (int j = 0; j < 8; ++j) {
      float t = x[j];
      if (LAYER == 1) t = fmaxf(0.f, fmaf(t, sc[j], sh[j]));
      acc[j] = fmaf(w, t, acc[j]);
    }
  };

  const int beg = offsets[v];
  const int end = offsets[v + 1];
  int i = beg;
  for (; i + 8 <= end; i += 8) {  // 8 edges, 4 independent chains
    uint4 ent[4];
    #pragma unroll
    for (int c = 0; c < 4; ++c) ent[c] = csr_ent[i + 2 * c + p];
    uint4 row[4];
    #pragma unroll
    for (int c = 0; c < 4; ++c)
      row[c] = *reinterpret_cast<const uint4*>(h_base + (ent[c].x + qb));
    #pragma unroll
    for (int c = 0; c < 4; ++c) body(row[c], wext(ent[c]));
  }
  for (; i + 2 <= end; i += 2) {
    const uint4 ent = csr_ent[i + p];
    const uint4 row = *reinterpret_cast<const uint4*>(h_base + (ent.x + qb));
    body(row, wext(ent));
  }
  if (i < end) {  // odd tail: p==1 half contributes w=0
    const uint4 ent = csr_ent[i];
    const uint4 row = *reinterpret_cast<const uint4*>(h_base + (ent.x + qb));
    body(row, p == 0 ? wext(ent) : 0.f);
  }

  #pragma unroll
  for (int j = 0; j < 8; ++j) acc[j] += __shfl_xor(acc[j], 32, 64);
  if (lane < 32) {
    uint4 o;
    o.x = pack2(f2bf(acc[0]), f2bf(acc[1]));
    o.y = pack2(f2bf(acc[2]), f2bf(acc[3]));
    o.z = pack2(f2bf(acc[4]), f2bf(acc[5]));
    o.w = pack2(f2bf(acc[6]), f2bf(acc[7]));
    agg[(size_t)v * 32 + q] = o;
  }
}

// Pre-pack W (fp32 64x64) into MFMA B-fragment layout as bf16.
__global__ __launch_bounds__(512) void wfrag_kernel(const float* __restrict__ W0,
                                                    const float* __restrict__ W1,
                                                    short* __restrict__ wf0,
                                                    short* __restrict__ wf1) {
  const int frag = threadIdx.x >> 6, lane = threadIdx.x & 63;
  const int c = frag >> 1, h = frag & 1;
  const int n = (c << 4) + (lane & 15);
  const int k0 = h * 32 + ((lane >> 4) << 3);
  short* o0 = wf0 + frag * 512 + lane * 8;
  short* o1 = wf1 + frag * 512 + lane * 8;
  #pragma unroll
  for (int i = 0; i < 8; ++i) {
    o0[i] = (short)f2bf(W0[(k0 + i) * 64 + n]);
    o1[i] = (short)f2bf(W1[(k0 + i) * 64 + n]);
  }
}

// y[r,f] = agg_bf16[r,:] @ W ; 8 MFMAs per 16-row block per wave; y stored bf16.
// Emits per-block partials: part[blk*320 + t*64+f] = sum_rows y, part[blk*320+256+f] = sum y^2.
__global__ __launch_bounds__(256) void mfma_matmul_kernel(
    const unsigned short* __restrict__ aggb, const short* __restrict__ wf,
    unsigned short* __restrict__ y_bf, float* __restrict__ part, int R) {
  const int tid = threadIdx.x;
  const int lane = tid & 63;
  const int wid = tid >> 6;

  short8 bfr[8];
  #pragma unroll
  for (int g = 0; g < 8; ++g)
    bfr[g] = *reinterpret_cast<const short8*>(wf + g * 512 + lane * 8);

  f32x4 csum[4];
  float ssq[4];
  #pragma unroll
  for (int c = 0; c < 4; ++c) { csum[c] = (f32x4){0.f, 0.f, 0.f, 0.f}; ssq[c] = 0.f; }

  const int nrb = (R + 15) >> 4;
  const int k0 = (lane >> 4) << 3;
  for (int rb = blockIdx.x * 4 + wid; rb < nrb; rb += gridDim.x * 4) {
    const int base = rb << 4;
    const int row = base + (lane & 15);
    short8 a0 = (short8){0, 0, 0, 0, 0, 0, 0, 0};
    short8 a1 = a0;
    if (row < R) {
      const short8* ap = reinterpret_cast<const short8*>(aggb + (size_t)row * 64 + k0);
      a0 = ap[0];
      a1 = ap[4];
    }
    f32x4 acc[4];
    #pragma unroll
    for (int c = 0; c < 4; ++c) {
      acc[c] = (f32x4){0.f, 0.f, 0.f, 0.f};
      acc[c] = __builtin_amdgcn_mfma_f32_16x16x32_bf16(a0, bfr[c * 2 + 0], acc[c], 0, 0, 0);
      acc[c] = __builtin_amdgcn_mfma_f32_16x16x32_bf16(a1, bfr[c * 2 + 1], acc[c], 0, 0, 0);
    }
    const int rbase = base + ((lane >> 4) << 2);
    #pragma unroll
    for (int c = 0; c < 4; ++c) {
      const int col = (c << 4) + (lane & 15);
      #pragma unroll
      for (int i = 0; i < 4; ++i) {
        const int r2 = rbase + i;
        if (r2 < R) {
          const float val = acc[c][i];
          y_bf[(size_t)r2 * 64 + col] = f2bf(val);
          csum[c][i] += val;
          ssq[c] += val * val;
        }
      }
    }
  }

  #pragma unroll
  for (int c = 0; c < 4; ++c) {
    #pragma unroll
    for (int i = 0; i < 4; ++i) {
      float v = csum[c][i];
      v += __shfl_xor(v, 16, 64);
      v += __shfl_xor(v, 32, 64);
      csum[c][i] = v;
    }
    float q = ssq[c];
    q += __shfl_xor(q, 16, 64);
    q += __shfl_xor(q, 32, 64);
    ssq[c] = q;
  }
  __shared__ float lcs[4][256];
  __shared__ float lsq[4][64];
  if (lane < 16) {
    #pragma unroll
    for (int c = 0; c < 4; ++c) {
      #pragma unroll
      for (int i = 0; i < 4; ++i) lcs[wid][i * 64 + (c << 4) + lane] = csum[c][i];
      lsq[wid][(c << 4) + lane] = ssq[c];
    }
  }
  __syncthreads();
  float s = lcs[0][tid] + lcs[1][tid] + lcs[2][tid] + lcs[3][tid];
  part[(size_t)blockIdx.x * 320 + tid] = s;
  if (tid < 64)
    part[(size_t)blockIdx.x * 320 + 256 + tid] =
        lsq[0][tid] + lsq[1][tid] + lsq[2][tid] + lsq[3][tid];
}

// Parallel deterministic reduce of part[nblk][320] -> red[320].
__global__ __launch_bounds__(1024) void reduce_part_kernel(const float* __restrict__ part,
                                                           float* __restrict__ red, int nblk) {
  __shared__ float lds[1024];
  const int tid = threadIdx.x;
  const int col = blockIdx.x * 16 + (tid & 15);
  const int r = tid >> 4;  // 0..63
  float s = 0.f;
  for (int bk = r; bk < nblk; bk += 64) s += part[(size_t)bk * 320 + col];
  lds[tid] = s;
  __syncthreads();
  #pragma unroll
  for (int off = 512; off >= 16; off >>= 1) {
    if (tid < off) lds[tid] += lds[tid + off];
    __syncthreads();
  }
  if (tid < 16) red[col] = lds[tid];
}

// layer-0 BN params from red[320]
__global__ __launch_bounds__(64) void bn_from_red_kernel(
    const float* __restrict__ red, const float* __restrict__ g, const float* __restrict__ b,
    float* __restrict__ scale, float* __restrict__ shiftv, float inv_count) {
  const int f = threadIdx.x;
  float sum = red[f] + red[64 + f] + red[128 + f] + red[192 + f];
  float mean = sum * inv_count;
  float var = red[256 + f] * inv_count - mean * mean;
  float sc = g[f] * rsqrtf(var + 1e-5f);
  scale[f] = sc;
  shiftv[f] = fmaf(-mean, sc, b[f]);
}

// layer-1: readout = red[0:256]/N (mean(agg)@W == mean(agg@W)) + BN params
__global__ __launch_bounds__(256) void finalize_from_red_kernel(
    const float* __restrict__ red, const float* __restrict__ g, const float* __restrict__ b,
    float* __restrict__ scale, float* __restrict__ shiftv, float inv_count,
    float* __restrict__ out_readout, float invN) {
  const int tid = threadIdx.x;
  out_readout[tid] = red[tid] * invN;
  if (tid < 64) {
    float sum = red[tid] + red[64 + tid] + red[128 + tid] + red[192 + tid];
    float mean = sum * inv_count;
    float var = red[256 + tid] * inv_count - mean * mean;
    float sc = g[tid] * rsqrtf(var + 1e-5f);
    scale[tid] = sc;
    shiftv[tid] = fmaf(-mean, sc, b[tid]);
  }
}

// final: out_fp32 = relu(y1_bf16 * scale + shift); 8 elems/thread
__global__ void bn_relu_out_kernel(const uint4* __restrict__ yb,
                                   const float* __restrict__ scale,
                                   const float* __restrict__ shiftv,
                                   float4* __restrict__ out, int n8) {
  int i = blockIdx.x * blockDim.x + threadIdx.x;
  if (i >= n8) return;
  const int f0 = (i & 7) << 3;
  uint4 u = yb[i];
  float x[8] = {bflo(u.x), bfhi(u.x), bflo(u.y), bfhi(u.y),
                bflo(u.z), bfhi(u.z), bflo(u.w), bfhi(u.w)};
  float4 o0, o1;
  o0.x = fmaxf(0.f, fmaf(x[0], scale[f0 + 0], shiftv[f0 + 0]));
  o0.y = fmaxf(0.f, fmaf(x[1], scale[f0 + 1], shiftv[f0 + 1]));
  o0.z = fmaxf(0.f, fmaf(x[2], scale[f0 + 2], shiftv[f0 + 2]));
  o0.w = fmaxf(0.f, fmaf(x[3], scale[f0 + 3], shiftv[f0 + 3]));
  o1.x = fmaxf(0.f, fmaf(x[4], scale[f0 + 4], shiftv[f0 + 4]));
  o1.y = fmaxf(0.f, fmaf(x[5], scale[f0 + 5], shiftv[f0 + 5]));
  o1.z = fmaxf(0.f, fmaf(x[6], scale[f0 + 6], shiftv[f0 + 6]));
  o1.w = fmaxf(0.f, fmaf(x[7], scale[f0 + 7], shiftv[f0 + 7]));
  out[i * 2 + 0] = o0;
  out[i * 2 + 1] = o1;
}

extern "C" void kernel_launch(void* const* d_in, const int* in_sizes, int n_in,
                              void* d_out, int out_size, void* d_ws, size_t ws_size,
                              hipStream_t stream) {
  const float* node_features = (const float*)d_in[0];
  const float* edges_weight  = (const float*)d_in[1];
  const int*   identities    = (const int*)d_in[2];
  const int*   edge_src      = (const int*)d_in[3];
  const int*   edge_dst      = (const int*)d_in[4];
  const float* pe            = (const float*)d_in[5];
  const float* W0            = (const float*)d_in[6];
  const float* W1            = (const float*)d_in[7];
  const float* g0            = (const float*)d_in[8];
  const float* b0            = (const float*)d_in[9];
  const float* g1            = (const float*)d_in[10];
  const float* b1            = (const float*)d_in[11];

  const int T = in_sizes[2];            // 4
  const int E = in_sizes[3];            // 800000
  const int F = in_sizes[8];            // 64
  const int N = in_sizes[0] / (T * F);  // 50000
  const int R = N * T;                  // 200000

  float* out = (float*)d_out;
  float* out_h = out;                            // (N,T,F) fp32
  float* out_readout = out + (size_t)N * T * F;  // (T,F)

  // ---- workspace layout ----
  char* ws = (char*)d_ws;
  size_t off = 0;
  auto alloc = [&](size_t bytes) -> void* {
    off = (off + 255) & ~(size_t)255;
    void* p = ws + off;
    off += bytes;
    return p;
  };
  int*    indeg    = (int*)alloc((size_t)N * sizeof(int));
  int*    partials = (int*)alloc(64 * sizeof(int));
  int*    base_    = (int*)alloc(64 * sizeof(int));
  int*    offsets  = (int*)alloc(((size_t)N + 1) * sizeof(int));
  int*    cursor   = (int*)alloc((size_t)N * sizeof(int));
  uint4v* csr_ent  = (uint4v*)alloc((size_t)E * 16);
  unsigned short* h0b  = (unsigned short*)alloc((size_t)N * TF * 2);  // h0 -> y0 -> y1
  unsigned short* aggb = (unsigned short*)alloc((size_t)N * TF * 2);
  short* wf0 = (short*)alloc(8 * 512 * sizeof(short));
  short* wf1 = (short*)alloc(8 * 512 * sizeof(short));
  const int MMB = 256;  // mfma matmul grid
  float* mm_part = (float*)alloc((size_t)MMB * 320 * sizeof(float));
  float* red     = (float*)alloc(320 * sizeof(float));
  float* scale0 = (float*)alloc(64 * sizeof(float));
  float* shift0 = (float*)alloc(64 * sizeof(float));
  float* scale1 = (float*)alloc(64 * sizeof(float));
  float* shift1 = (float*)alloc(64 * sizeof(float));
  (void)ws_size;

  const int nb = (N + 1023) / 1024;  // <=64

  // ---- CSR build ----
  hipMemsetAsync(indeg, 0, (size_t)N * sizeof(int), stream);
  hipLaunchKernelGGL(hist_kernel, dim3((E + 255) / 256), dim3(256), 0, stream, edge_dst, indeg, E);
  hipLaunchKernelGGL(scan_part1, dim3(nb), dim3(1024), 0, stream, indeg, partials, N);
  hipLaunchKernelGGL(scan_part2, dim3(1), dim3(64), 0, stream, partials, base_, offsets, nb, N);
  hipLaunchKernelGGL(scan_part3, dim3(nb), dim3(1024), 0, stream, indeg, base_, offsets, cursor, N);
  hipLaunchKernelGGL(fill_kernel, dim3((E + 255) / 256), dim3(256), 0, stream,
                     edge_src, edge_dst, edges_weight, cursor, csr_ent, E);

  // ---- W fragments + prep ----
  hipLaunchKernelGGL(wfrag_kernel, dim3(1), dim3(512), 0, stream, W0, W1, wf0, wf1);
  hipLaunchKernelGGL(prep_kernel, dim3(2048), dim3(256), 0, stream,
                     node_features, pe, identities, (uint2*)h0b, (N * TF) / 4);

  const int agg_blocks = (N + 3) / 4;

  // ---- layer 0 ----
  hipLaunchKernelGGL((aggregate_kernel<0>), dim3(agg_blocks), dim3(256), 0, stream,
                     (const char*)h0b, offsets, (const uint4*)csr_ent,
                     nullptr, nullptr, (uint4*)aggb, N);
  hipLaunchKernelGGL(mfma_matmul_kernel, dim3(MMB), dim3(256), 0, stream,
                     aggb, wf0, h0b /*y0b*/, mm_part, R);
  hipLaunchKernelGGL(reduce_part_kernel, dim3(20), dim3(1024), 0, stream, mm_part, red, MMB);
  hipLaunchKernelGGL(bn_from_red_kernel, dim3(1), dim3(64), 0, stream,
                     red, g0, b0, scale0, shift0, 1.0f / (float)R);

  // ---- layer 1 (BN0+ReLU fused into gather) ----
  hipLaunchKernelGGL((aggregate_kernel<1>), dim3(agg_blocks), dim3(256), 0, stream,
                     (const char*)h0b /*y0b*/, offsets, (const uint4*)csr_ent,
                     scale0, shift0, (uint4*)aggb, N);
  hipLaunchKernelGGL(mfma_matmul_kernel, dim3(MMB), dim3(256), 0, stream,
                     aggb, wf1, h0b /*y1b*/, mm_part, R);
  hipLaunchKernelGGL(reduce_part_kernel, dim3(20), dim3(1024), 0, stream, mm_part, red, MMB);
  hipLaunchKernelGGL(finalize_from_red_kernel, dim3(1), dim3(256), 0, stream,
                     red, g1, b1, scale1, shift1, 1.0f / (float)R,
                     out_readout, 1.0f / (float)N);

  // ---- final BN1 + ReLU: out_fp32 = relu(bn(y1_bf16)) ----
  hipLaunchKernelGGL(bn_relu_out_kernel, dim3((R * 8 + 255) / 256), dim3(256), 0, stream,
                     (const uint4*)h0b, scale1, shift1, (float4*)out_h, R * 8);
}